// Round 8
// baseline (1147.623 us; speedup 1.0000x reference)
//
#include <hip/hip_runtime.h>

#define DD 128

typedef __attribute__((ext_vector_type(8))) short bf16x8;
typedef __attribute__((ext_vector_type(4))) short bf16x4;
typedef __attribute__((ext_vector_type(4))) float f32x4;
typedef unsigned short u16;

__device__ __forceinline__ unsigned short f2bf(float f) {
  union { float f; unsigned u; } v; v.f = f;
  unsigned u = v.u;
  return (unsigned short)((u + 0x7FFFu + ((u >> 16) & 1u)) >> 16);
}
__device__ __forceinline__ float bf2f(unsigned short h) {
  union { unsigned u; float f; } v; v.u = ((unsigned)h) << 16; return v.f;
}
__device__ __forceinline__ bf16x8 pack8(f32x4 a, f32x4 b) {
  bf16x8 r;
  r[0] = (short)f2bf(a.x); r[1] = (short)f2bf(a.y);
  r[2] = (short)f2bf(a.z); r[3] = (short)f2bf(a.w);
  r[4] = (short)f2bf(b.x); r[5] = (short)f2bf(b.y);
  r[6] = (short)f2bf(b.z); r[7] = (short)f2bf(b.w);
  return r;
}

// edge_index may be int32 or int64; detect via zero high words.
__device__ __forceinline__ bool idx_is64(const int* p) {
  return (p[1] | p[3] | p[5] | p[7]) == 0;
}
__device__ __forceinline__ int ld_idx(const int* p, long long i, bool is64) {
  return is64 ? (int)((const long long*)p)[i] : p[i];
}

__global__ void k_count(const int* __restrict__ idx, int* __restrict__ cnt, int E) {
  int e = blockIdx.x * blockDim.x + threadIdx.x;
  if (e >= E) return;
  bool is64 = idx_is64(idx);
  int d = ld_idx(idx, (long long)E + e, is64);
  atomicAdd(&cnt[d], 1);
}

__global__ __launch_bounds__(1024) void k_scan(const int* __restrict__ cnt,
    int* __restrict__ row_start, int* __restrict__ cursor, int N) {
  __shared__ int part[1024];
  int t = threadIdx.x;
  int chunk = (N + 1023) >> 10;
  int lo = t * chunk, hi = lo + chunk; if (hi > N) hi = N; if (lo > N) lo = N;
  int s = 0;
  for (int i = lo; i < hi; ++i) s += cnt[i];
  part[t] = s;
  __syncthreads();
  for (int off = 1; off < 1024; off <<= 1) {
    int v = (t >= off) ? part[t - off] : 0;
    __syncthreads();
    part[t] += v;
    __syncthreads();
  }
  int run = (t == 0) ? 0 : part[t - 1];
  for (int i = lo; i < hi; ++i) {
    row_start[i] = run; cursor[i] = run; run += cnt[i];
  }
  if (t == 1023) row_start[N] = part[1023];
}

// CSR fill; materializes src_csr and dst_csr per CSR slot.
__global__ void k_fill(const int* __restrict__ idx, int* __restrict__ cursor,
                       int* __restrict__ edge_of, int* __restrict__ src_csr,
                       int* __restrict__ dst_csr, int E) {
  int e = blockIdx.x * blockDim.x + threadIdx.x;
  if (e >= E) return;
  bool is64 = idx_is64(idx);
  int s = ld_idx(idx, e, is64);
  int d = ld_idx(idx, (long long)E + e, is64);
  int pos = atomicAdd(&cursor[d], 1);
  edge_of[pos] = e;
  src_csr[pos] = s;
  dst_csr[pos] = d;
}

// Fused per-layer edge kernel. Each wave owns 64 consecutive CSR edges:
//  - rel GEMM on 4x 16-edge tiles (weights in 32KB swizzled LDS)
//  - message partial sums x[src]*ea, segment-reduced over the sorted dst
//    dimension via 16-lane shuffles + carry; complete segments -> plain f32
//    store to aggsum, boundary segments -> unsafeAtomicAdd (rare).
// MODE 0: ea/x read f32 via edge_of/src_csr (orig order), GEMM out -> bf16 CSR.
// MODE 1: ea bf16 CSR seq, x bf16 post-BN; GEMM out -> bf16 CSR.
// MODE 2: like 1 but GEMM out -> f32 scatter to out_ea[edge_of[k]].
template <int MODE>
__global__ __launch_bounds__(256, 2) void k_layer(
    const float* __restrict__ x0, const u16* __restrict__ xpin,
    const float* __restrict__ ea0, const u16* __restrict__ eain,
    u16* __restrict__ eabout, float* __restrict__ eafout,
    float* __restrict__ aggsum,
    const int* __restrict__ row_start, const int* __restrict__ edge_of,
    const int* __restrict__ src_csr, const int* __restrict__ dst_csr,
    const float* __restrict__ w_rel, const float* __restrict__ b_rel,
    int E) {
  __shared__ short Wl[16384];
  for (int q = threadIdx.x; q < 4096; q += 256) {
    int off = q * 4;
    int f = off >> 7, d = off & 127;
    f32x4 w = *(const f32x4*)(w_rel + off);
    unsigned byte = ((unsigned)(f * 256 + d * 2)) ^ (unsigned)((f & 7) << 4);
    bf16x4 s4;
    s4[0] = (short)f2bf(w.x); s4[1] = (short)f2bf(w.y);
    s4[2] = (short)f2bf(w.z); s4[3] = (short)f2bf(w.w);
    *(bf16x4*)((char*)Wl + byte) = s4;
  }
  __syncthreads();
  int wid = blockIdx.x * 4 + (threadIdx.x >> 6);
  int wk0 = wid * 64;
  if (wk0 >= E) return;
  int lane = threadIdx.x & 63, r = lane & 15, g = lane >> 4;

  float carry[32];
  int cdst = -1;
#pragma unroll
  for (int ch = 0; ch < 32; ++ch) carry[ch] = 0.f;

#pragma unroll 1
  for (int st = 0; st < 4; ++st) {
    int k0 = wk0 + st * 16;
    int kr = k0 + r;
    int dr = dst_csr[kr];
    int sn = src_csr[kr];
    bf16x8 a8[4];
    float m[32];
    if constexpr (MODE == 0) {
      int e = edge_of[kr];
      const float* ep = ea0 + (size_t)e * DD;
      const float* xp = x0 + (size_t)sn * DD;
#pragma unroll
      for (int ks = 0; ks < 4; ++ks) {
        int c0 = ks * 32 + g * 8;
        f32x4 e0 = *(const f32x4*)(ep + c0), e1 = *(const f32x4*)(ep + c0 + 4);
        f32x4 xv0 = *(const f32x4*)(xp + c0), xv1 = *(const f32x4*)(xp + c0 + 4);
        a8[ks] = pack8(e0, e1);
#pragma unroll
        for (int j = 0; j < 4; ++j) {
          m[ks * 8 + j] = e0[j] * xv0[j];
          m[ks * 8 + 4 + j] = e1[j] * xv1[j];
        }
      }
    } else {
      const u16* ep = eain + (size_t)kr * DD;
      const u16* xp = xpin + (size_t)sn * DD;
#pragma unroll
      for (int ks = 0; ks < 4; ++ks) {
        int c0 = ks * 32 + g * 8;
        bf16x8 ev = *(const bf16x8*)(ep + c0);
        bf16x8 xv = *(const bf16x8*)(xp + c0);
        a8[ks] = ev;
#pragma unroll
        for (int j = 0; j < 8; ++j)
          m[ks * 8 + j] = bf2f((u16)ev[j]) * bf2f((u16)xv[j]);
      }
    }
    // ---- rel GEMM on this 16-edge tile ----
    f32x4 acc[8];
#pragma unroll
    for (int ct = 0; ct < 8; ++ct) acc[ct] = (f32x4){0.f, 0.f, 0.f, 0.f};
#pragma unroll
    for (int ct = 0; ct < 8; ++ct) {
      int f = ct * 16 + r;
      unsigned base = (unsigned)(f * 256);
      unsigned sw = (unsigned)((f & 7) << 4);
#pragma unroll
      for (int ks = 0; ks < 4; ++ks) {
        unsigned byte = (base + (unsigned)(ks * 64 + g * 16)) ^ sw;
        bf16x8 bb = *(const bf16x8*)((const char*)Wl + byte);
        acc[ct] = __builtin_amdgcn_mfma_f32_16x16x32_bf16(a8[ks], bb, acc[ct], 0, 0, 0);
      }
    }
    size_t orow[4];
#pragma unroll
    for (int j = 0; j < 4; ++j) {
      int kk = k0 + g * 4 + j;
      if constexpr (MODE == 2) orow[j] = (size_t)edge_of[kk];
      else                     orow[j] = (size_t)kk;
    }
#pragma unroll
    for (int ct = 0; ct < 8; ++ct) {
      int col = ct * 16 + r;
      float bv = b_rel[col];
#pragma unroll
      for (int j = 0; j < 4; ++j) {
        float v = acc[ct][j] + bv;
        if constexpr (MODE == 2) eafout[orow[j] * DD + col] = v;
        else                     eabout[orow[j] * DD + col] = f2bf(v);
      }
    }
    // ---- stale-carry flush (segment ended at previous sub-tile) ----
    int d0 = __shfl(dr, 0, 16);
    if (cdst >= 0 && cdst != d0) {
      if (r == 0) {
        int s0d = row_start[cdst], s1d = row_start[cdst + 1];
        bool cont = (s0d >= wk0) && (s1d <= wk0 + 64);
        float* dp = aggsum + (size_t)cdst * DD;
        if (cont) {
#pragma unroll
          for (int ks = 0; ks < 4; ++ks) {
            f32x4 lo, hi;
#pragma unroll
            for (int j = 0; j < 4; ++j) { lo[j] = carry[ks * 8 + j]; hi[j] = carry[ks * 8 + 4 + j]; }
            *(f32x4*)(dp + ks * 32 + g * 8) = lo;
            *(f32x4*)(dp + ks * 32 + g * 8 + 4) = hi;
          }
        } else {
#pragma unroll
          for (int ks = 0; ks < 4; ++ks)
#pragma unroll
            for (int j = 0; j < 8; ++j)
              unsafeAtomicAdd(dp + ks * 32 + g * 8 + j, carry[ks * 8 + j]);
        }
      }
      cdst = -1;
    }
    // ---- segmented inclusive scan over r (16-lane groups) ----
#pragma unroll
    for (int s = 1; s < 16; s <<= 1) {
      int dprev = __shfl_up(dr, s, 16);
      bool take = (r >= s) && (dprev == dr);
#pragma unroll
      for (int ch = 0; ch < 32; ++ch) {
        float v = __shfl_up(m[ch], s, 16);
        m[ch] += take ? v : 0.f;
      }
    }
    // head segment continues previous carry
    if (dr == cdst) {
#pragma unroll
      for (int ch = 0; ch < 32; ++ch) m[ch] += carry[ch];
    }
    // ---- flush closed segments (tail lanes, r<15) ----
    int dnext = __shfl_down(dr, 1, 16);
    bool tail = (r < 15) && (dnext != dr);
    if (tail) {
      int s0d = row_start[dr], s1d = row_start[dr + 1];
      bool cont = (s0d >= wk0) && (s1d <= wk0 + 64);
      float* dp = aggsum + (size_t)dr * DD;
      if (cont) {
#pragma unroll
        for (int ks = 0; ks < 4; ++ks) {
          f32x4 lo, hi;
#pragma unroll
          for (int j = 0; j < 4; ++j) { lo[j] = m[ks * 8 + j]; hi[j] = m[ks * 8 + 4 + j]; }
          *(f32x4*)(dp + ks * 32 + g * 8) = lo;
          *(f32x4*)(dp + ks * 32 + g * 8 + 4) = hi;
        }
      } else {
#pragma unroll
        for (int ks = 0; ks < 4; ++ks)
#pragma unroll
          for (int j = 0; j < 8; ++j)
            unsafeAtomicAdd(dp + ks * 32 + g * 8 + j, m[ks * 8 + j]);
      }
    }
    // ---- new carry = open segment ending at r=15 ----
#pragma unroll
    for (int ch = 0; ch < 32; ++ch) carry[ch] = __shfl(m[ch], 15, 16);
    cdst = __shfl(dr, 15, 16);
  }
  // ---- final carry flush ----
  if (cdst >= 0 && r == 0) {
    int s0d = row_start[cdst], s1d = row_start[cdst + 1];
    bool cont = (s0d >= wk0) && (s1d <= wk0 + 64);
    float* dp = aggsum + (size_t)cdst * DD;
    if (cont) {
#pragma unroll
      for (int ks = 0; ks < 4; ++ks) {
        f32x4 lo, hi;
#pragma unroll
        for (int j = 0; j < 4; ++j) { lo[j] = carry[ks * 8 + j]; hi[j] = carry[ks * 8 + 4 + j]; }
        *(f32x4*)(dp + ks * 32 + g * 8) = lo;
        *(f32x4*)(dp + ks * 32 + g * 8 + 4) = hi;
      }
    } else {
#pragma unroll
      for (int ks = 0; ks < 4; ++ks)
#pragma unroll
        for (int j = 0; j < 8; ++j)
          unsafeAtomicAdd(dp + ks * 32 + g * 8 + j, carry[ks * 8 + j]);
    }
  }
}

// Node GEMM: xn = (aggsum/deg) @ W_in^T + x @ W_self^T + b_self + (deg>0)*b_in.
template <typename TX, typename TO, bool STATS>
__global__ __launch_bounds__(256, 2) void k_node(const float* __restrict__ aggsum,
    const TX* __restrict__ xc, const float* __restrict__ W_in,
    const float* __restrict__ W_self, const float* __restrict__ b_in,
    const float* __restrict__ b_self, const int* __restrict__ row_start,
    TO* __restrict__ xn, float* __restrict__ gsum, float* __restrict__ gssq,
    int ntiles) {
  __shared__ short Wl[DD * 256];
  for (int q = threadIdx.x; q < DD * 256 / 4; q += 256) {
    int off = q * 4;
    int f = off >> 8, k = off & 255;
    f32x4 w = (k < 128) ? *(const f32x4*)(W_in + f * 128 + k)
                        : *(const f32x4*)(W_self + f * 128 + (k - 128));
    unsigned byte = ((unsigned)(f * 512 + k * 2)) ^ (unsigned)((f & 7) << 4);
    bf16x4 s4;
    s4[0] = (short)f2bf(w.x); s4[1] = (short)f2bf(w.y);
    s4[2] = (short)f2bf(w.z); s4[3] = (short)f2bf(w.w);
    *(bf16x4*)((char*)Wl + byte) = s4;
  }
  __syncthreads();
  int wave = threadIdx.x >> 6, lane = threadIdx.x & 63;
  int tile = blockIdx.x * 4 + wave;
  if (tile >= ntiles) return;
  int r = lane & 15, g = lane >> 4;
  int arowi = tile * 16 + r;
  int dr0 = row_start[arowi], dr1 = row_start[arowi + 1];
  float inv = (dr1 > dr0) ? 1.0f / (float)(dr1 - dr0) : 0.0f;
  const float* arow = aggsum + (size_t)arowi * DD;
  const TX* xrow = xc + (size_t)arowi * DD;
  bf16x8 a[8];
#pragma unroll
  for (int ks = 0; ks < 4; ++ks) {
    const float* p = arow + ks * 32 + g * 8;
    f32x4 v0 = *(const f32x4*)p * inv;
    f32x4 v1 = *(const f32x4*)(p + 4) * inv;
    a[ks] = pack8(v0, v1);
  }
#pragma unroll
  for (int ks = 0; ks < 4; ++ks) {
    int c0 = ks * 32 + g * 8;
    if constexpr (sizeof(TX) == 2) {
      a[4 + ks] = *(const bf16x8*)(xrow + c0);
    } else {
      const float* p = (const float*)xrow + c0;
      a[4 + ks] = pack8(*(const f32x4*)p, *(const f32x4*)(p + 4));
    }
  }
  f32x4 acc[8];
#pragma unroll
  for (int ct = 0; ct < 8; ++ct) acc[ct] = (f32x4){0.f, 0.f, 0.f, 0.f};
#pragma unroll
  for (int ct = 0; ct < 8; ++ct) {
    int f = ct * 16 + r;
    unsigned base = (unsigned)(f * 512);
    unsigned sw = (unsigned)((f & 7) << 4);
#pragma unroll
    for (int ks = 0; ks < 8; ++ks) {
      unsigned byte = (base + (unsigned)(ks * 64 + g * 16)) ^ sw;
      bf16x8 b = *(const bf16x8*)((const char*)Wl + byte);
      acc[ct] = __builtin_amdgcn_mfma_f32_16x16x32_bf16(a[ks], b, acc[ct], 0, 0, 0);
    }
  }
  int nbase = tile * 16;
  float degmask[4];
#pragma unroll
  for (int j = 0; j < 4; ++j) {
    int nn = nbase + g * 4 + j;
    degmask[j] = (row_start[nn + 1] > row_start[nn]) ? 1.0f : 0.0f;
  }
#pragma unroll
  for (int ct = 0; ct < 8; ++ct) {
    int col = ct * 16 + r;
    float bi = b_in[col], bs = b_self[col];
    float s = 0.f, s2 = 0.f;
#pragma unroll
    for (int j = 0; j < 4; ++j) {
      float v = acc[ct][j] + bs + bi * degmask[j];
      if constexpr (sizeof(TO) == 2) xn[(size_t)(nbase + g * 4 + j) * DD + col] = (TO)f2bf(v);
      else                            xn[(size_t)(nbase + g * 4 + j) * DD + col] = (TO)v;
      s += v; s2 += v * v;
    }
    if constexpr (STATS) {
      s += __shfl_xor(s, 16);  s += __shfl_xor(s, 32);
      s2 += __shfl_xor(s2, 16); s2 += __shfl_xor(s2, 32);
      if (g == 0) { atomicAdd(&gsum[col], s); atomicAdd(&gssq[col], s2); }
    }
  }
}

__global__ void k_bnfin(float* __restrict__ gsum, float* __restrict__ gssq,
    const float* __restrict__ gamma, const float* __restrict__ beta,
    float* __restrict__ scale, float* __restrict__ shift, int N) {
  int d = threadIdx.x;
  float mu = gsum[d] / (float)N;
  float var = gssq[d] / (float)N - mu * mu;
  float rs = rsqrtf(var + 1e-5f);
  float sc = rs * gamma[d];
  scale[d] = sc;
  shift[d] = beta[d] - mu * sc;
  gsum[d] = 0.f;
  gssq[d] = 0.f;
}

// xpost = relu(xb*scale + shift), bf16 -> bf16, vectorized x8.
__global__ void k_bnapply(const u16* __restrict__ xb, u16* __restrict__ xpost,
                          const float* __restrict__ scale,
                          const float* __restrict__ shift, int total8) {
  int i = blockIdx.x * blockDim.x + threadIdx.x;
  if (i >= total8) return;
  bf16x8 v = ((const bf16x8*)xb)[i];
  int c0 = (i * 8) & 127;
  bf16x8 o;
#pragma unroll
  for (int j = 0; j < 8; ++j) {
    float f = fmaxf(bf2f((u16)v[j]) * scale[c0 + j] + shift[c0 + j], 0.f);
    o[j] = (short)f2bf(f);
  }
  ((bf16x8*)xpost)[i] = o;
}

static inline size_t alignup(size_t v, size_t a) { return (v + a - 1) & ~(a - 1); }

extern "C" void kernel_launch(void* const* d_in, const int* in_sizes, int n_in,
                              void* d_out, int out_size, void* d_ws, size_t ws_size,
                              hipStream_t stream) {
  const float* x0     = (const float*)d_in[0];
  const float* ea0    = (const float*)d_in[1];
  const float* w_self = (const float*)d_in[2];
  const float* b_self = (const float*)d_in[3];
  const float* w_in   = (const float*)d_in[4];
  const float* b_in   = (const float*)d_in[5];
  const float* w_rel  = (const float*)d_in[6];
  const float* b_rel  = (const float*)d_in[7];
  const float* gamma  = (const float*)d_in[8];
  const float* beta   = (const float*)d_in[9];
  const int*   idx    = (const int*)d_in[10];

  const int N = in_sizes[0] / DD;
  const int E = in_sizes[1] / DD;

  char* w = (char*)d_ws;
  size_t off = 0;
  int* cnt       = (int*)(w + off); off = alignup(off + (size_t)N * 4, 256);
  int* row_start = (int*)(w + off); off = alignup(off + (size_t)(N + 1) * 4, 256);
  int* cursor    = (int*)(w + off); off = alignup(off + (size_t)N * 4, 256);
  int* edge_of   = (int*)(w + off); off = alignup(off + (size_t)E * 4, 256);
  int* src_csr   = (int*)(w + off); off = alignup(off + (size_t)E * 4, 256);
  int* dst_csr   = (int*)(w + off); off = alignup(off + (size_t)E * 4, 256);
  float* gstats  = (float*)(w + off); off = alignup(off + 256 * 4, 256);
  float* scale   = (float*)(w + off); off = alignup(off + 128 * 4, 256);
  float* shift   = (float*)(w + off); off = alignup(off + 128 * 4, 256);
  float* aggsum  = (float*)(w + off); off = alignup(off + (size_t)N * DD * 4, 256);
  u16* xbA       = (u16*)(w + off); off = alignup(off + (size_t)N * DD * 2, 256);
  u16* xpost     = (u16*)(w + off); off = alignup(off + (size_t)N * DD * 2, 256);
  u16* eaA       = (u16*)(w + off); off = alignup(off + (size_t)E * DD * 2, 256);
  u16* eaB       = (u16*)(w + off); off = alignup(off + (size_t)E * DD * 2, 256);
  float* gsum = gstats, *gssq = gstats + 128;
  (void)ws_size; (void)n_in; (void)out_size;

  float* out_x  = (float*)d_out;
  float* out_ea = out_x + (size_t)N * DD;

  // ---- CSR build ----
  (void)hipMemsetAsync(cnt, 0, (size_t)N * 4, stream);
  int ethreads = 256, eblocks = (E + ethreads - 1) / ethreads;
  k_count<<<eblocks, ethreads, 0, stream>>>(idx, cnt, E);
  k_scan<<<1, 1024, 0, stream>>>(cnt, row_start, cursor, N);
  k_fill<<<eblocks, ethreads, 0, stream>>>(idx, cursor, edge_of, src_csr, dst_csr, E);
  (void)hipMemsetAsync(gstats, 0, 256 * 4, stream);
  (void)hipMemsetAsync(aggsum, 0, (size_t)N * DD * 4, stream);

  const int ntN = N / 16;
  const int nodeBlocks = (ntN + 3) / 4;
  const int layerBlocks = (E / 64 + 3) / 4;    // wave per 64 CSR edges
  const int bnBlocks = ((size_t)N * DD / 8 + 255) / 256;

  // ---- layer 0 ----
  k_layer<0><<<layerBlocks, 256, 0, stream>>>(x0, nullptr, ea0, nullptr,
      eaA, nullptr, aggsum, row_start, edge_of, src_csr, dst_csr,
      w_rel, b_rel, E);
  k_node<float, u16, true><<<nodeBlocks, 256, 0, stream>>>(aggsum, x0,
      w_in, w_self, b_in, b_self, row_start, xbA, gsum, gssq, ntN);
  k_bnfin<<<1, 128, 0, stream>>>(gsum, gssq, gamma, beta, scale, shift, N);
  k_bnapply<<<bnBlocks, 256, 0, stream>>>(xbA, xpost, scale, shift, N * DD / 8);
  (void)hipMemsetAsync(aggsum, 0, (size_t)N * DD * 4, stream);

  // ---- layer 1 ----
  k_layer<1><<<layerBlocks, 256, 0, stream>>>(nullptr, xpost, nullptr, eaA,
      eaB, nullptr, aggsum, row_start, edge_of, src_csr, dst_csr,
      w_rel + DD * DD, b_rel + DD, E);
  k_node<u16, u16, true><<<nodeBlocks, 256, 0, stream>>>(aggsum, xpost,
      w_in + DD * DD, w_self + DD * DD, b_in + DD, b_self + DD,
      row_start, xbA, gsum, gssq, ntN);
  k_bnfin<<<1, 128, 0, stream>>>(gsum, gssq, gamma + DD, beta + DD, scale, shift, N);
  k_bnapply<<<bnBlocks, 256, 0, stream>>>(xbA, xpost, scale, shift, N * DD / 8);
  (void)hipMemsetAsync(aggsum, 0, (size_t)N * DD * 4, stream);

  // ---- layer 2 ----
  k_layer<2><<<layerBlocks, 256, 0, stream>>>(nullptr, xpost, nullptr, eaB,
      nullptr, out_ea, aggsum, row_start, edge_of, src_csr, dst_csr,
      w_rel + 2 * DD * DD, b_rel + 2 * DD, E);
  k_node<u16, float, false><<<nodeBlocks, 256, 0, stream>>>(aggsum, xpost,
      w_in + 2 * DD * DD, w_self + 2 * DD * DD, b_in + 2 * DD, b_self + 2 * DD,
      row_start, out_x, gsum, gssq, ntN);
}